// Round 1
// baseline (1041.851 us; speedup 1.0000x reference)
//
#include <hip/hip_runtime.h>
#include <hip/hip_bf16.h>
#include <stdint.h>

// Locally connected 2d on MI355X.
// out[b,o,h,w] = sum_{c,i,j} F[b,c,h+i,w+j] * W[h,w,o,c,i,j] + bias[h,w,o]
// B=32, Cin=Cout=64, H=W=64, K=3, Hout=Wout=62.
//
// Memory-bound: weights = 567 MB read exactly once. One wave per (h,w)
// location; per-location GEMM M=32(b) x N=64(o) x K=576 via
// mfma_f32_16x16x32_bf16. Weights feed B-fragments directly from global
// (K-contiguous per o row), converted fp32->bf16 (RNE) in registers.
// Patches staged through a tiny 2-chunk LDS ring in A-fragment-natural
// layout. Single-wave workgroups -> no __syncthreads needed (compiler
// lgkmcnt ordering covers the intra-wave LDS RAW).

#define B_     32
#define CIN_   64
#define H_     64
#define W_     64
#define COUT_  64
#define HOUT_  62
#define WOUT_  62
#define NLOC   (HOUT_ * WOUT_)   // 3844
#define KTOT   (CIN_ * 9)        // 576
#define NKT    (KTOT / 32)       // 18 MFMA K-steps

typedef float f32x4 __attribute__((ext_vector_type(4)));
typedef short s16x8 __attribute__((ext_vector_type(8)));

// feature offset (in floats) for unrolled k = c*9 + i*3 + j
#define FOFF(k) (((k) / 9) * (H_ * W_) + ((((k) % 9) / 3) * W_) + (((k) % 9) % 3))

// pack two fp32 -> two bf16 (RNE), lo in low half
__device__ __forceinline__ uint32_t pk_bf16(float lo, float hi) {
  uint32_t ul = __builtin_bit_cast(uint32_t, lo);
  uint32_t uh = __builtin_bit_cast(uint32_t, hi);
  ul = (ul + 0x7fffu + ((ul >> 16) & 1u)) >> 16;
  uh = (uh + 0x7fffu + ((uh >> 16) & 1u));
  return ul | (uh & 0xffff0000u);
}

__global__ void LocallyConnected2d_41102837022853_kernel(
    const float* __restrict__ F, const float* __restrict__ Wt,
    const float* __restrict__ Bi, float* __restrict__ Out) {
  // LDS ring: 2 chunks x 32 b-rows x (32 bf16 k's + 8 pad) -> 80B rows,
  // 16B-aligned, A-frag b128 reads land at the 8-bank-cycle minimum.
  __shared__ __align__(16) uint16_t PL[2][B_][40];

  const int lane = threadIdx.x;             // 0..63, single wave per block
  const int bid = blockIdx.x;

  // XCD-grouping swizzle: hw assigns xcd ~ blockIdx%8; give each XCD a
  // contiguous run of w-adjacent locations so scattered 4B output stores
  // from neighboring locations merge into full lines inside one L2.
  const int xcd = bid & 7, slot = bid >> 3;
  const int loc = xcd * 480 + (xcd < 4 ? xcd : 4) + slot;  // bijective on [0,3844)
  const int h = loc / WOUT_, w = loc % WOUT_;

  const int l15 = lane & 15, l4 = lane >> 4;   // fragment coords
  const int gb = lane & 31, hb = lane >> 5;    // gather coords (b, k-half)

  const float* fbase = F + gb * (CIN_ * H_ * W_) + h * W_ + w;
  // B-frag lane base: o = nt*16 + l15 (row stride 576), k-subslice l4*8
  const float* wlane = Wt + (size_t)loc * (COUT_ * KTOT) + (size_t)l15 * KTOT + l4 * 8;

  float gv[16];       // gathered features for next chunk
  f32x4 wv[4][2];     // fp32 weight fragments for current kt

  // ---- prologue: gather patch chunk 0 -> LDS buf 0 ----
#pragma unroll
  for (int s = 0; s < 8; ++s) {
    const int ke = 4 * s;  // kt = 0
    const int off0 = hb ? FOFF(ke + 2) : FOFF(ke);
    const int off1 = hb ? FOFF(ke + 3) : FOFF(ke + 1);
    gv[2 * s] = fbase[off0];
    gv[2 * s + 1] = fbase[off1];
  }
#pragma unroll
  for (int s = 0; s < 8; ++s)
    ((uint32_t*)PL[0][gb])[2 * s + hb] = pk_bf16(gv[2 * s], gv[2 * s + 1]);

  // ---- prologue: weight loads for kt = 0 ----
#pragma unroll
  for (int nt = 0; nt < 4; ++nt) {
    const float* p = wlane + nt * (16 * KTOT);
    wv[nt][0] = *(const f32x4*)p;
    wv[nt][1] = *(const f32x4*)(p + 4);
  }

  f32x4 acc[2][4] = {};

#pragma unroll
  for (int kt = 0; kt < NKT; ++kt) {
    const int buf = kt & 1;

    // 1. convert current weights fp32 -> bf16 B-fragments
    s16x8 bfrag[4];
#pragma unroll
    for (int nt = 0; nt < 4; ++nt) {
      union { uint32_t u[4]; s16x8 v; } t;
      t.u[0] = pk_bf16(wv[nt][0][0], wv[nt][0][1]);
      t.u[1] = pk_bf16(wv[nt][0][2], wv[nt][0][3]);
      t.u[2] = pk_bf16(wv[nt][1][0], wv[nt][1][1]);
      t.u[3] = pk_bf16(wv[nt][1][2], wv[nt][1][3]);
      bfrag[nt] = t.v;
    }

    // 2+3. prefetch weights & gather features for kt+1 (stay in flight
    // under the MFMAs below)
    if (kt + 1 < NKT) {
#pragma unroll
      for (int nt = 0; nt < 4; ++nt) {
        const float* p = wlane + nt * (16 * KTOT) + (kt + 1) * 32;
        wv[nt][0] = *(const f32x4*)p;
        wv[nt][1] = *(const f32x4*)(p + 4);
      }
#pragma unroll
      for (int s = 0; s < 8; ++s) {
        const int ke = (kt + 1) * 32 + 4 * s;
        const int off0 = hb ? FOFF(ke + 2) : FOFF(ke);
        const int off1 = hb ? FOFF(ke + 3) : FOFF(ke + 1);
        gv[2 * s] = fbase[off0];
        gv[2 * s + 1] = fbase[off1];
      }
    }

    // 4. A-fragments from LDS (natural layout: b128 of 8 consecutive k's)
    s16x8 a0 = *(const s16x8*)&PL[buf][l15][l4 * 8];
    s16x8 a1 = *(const s16x8*)&PL[buf][16 + l15][l4 * 8];

    // 5. 8 MFMAs: D[m=b][n=o]
#pragma unroll
    for (int nt = 0; nt < 4; ++nt) {
      acc[0][nt] = __builtin_amdgcn_mfma_f32_16x16x32_bf16(a0, bfrag[nt], acc[0][nt], 0, 0, 0);
      acc[1][nt] = __builtin_amdgcn_mfma_f32_16x16x32_bf16(a1, bfrag[nt], acc[1][nt], 0, 0, 0);
    }

    // 6. commit gathered chunk kt+1 into the other ring slot
    if (kt + 1 < NKT) {
#pragma unroll
      for (int s = 0; s < 8; ++s)
        ((uint32_t*)PL[buf ^ 1][gb])[2 * s + hb] = pk_bf16(gv[2 * s], gv[2 * s + 1]);
    }
  }

  // ---- epilogue: bias + store. C/D layout: col(o)=lane&15, row(b)=l4*4+r.
#pragma unroll
  for (int nt = 0; nt < 4; ++nt) {
    const int o = nt * 16 + l15;
    const float bv = Bi[loc * COUT_ + o];
#pragma unroll
    for (int mt = 0; mt < 2; ++mt) {
#pragma unroll
      for (int r = 0; r < 4; ++r) {
        const int b = mt * 16 + l4 * 4 + r;
        Out[(size_t)(b * COUT_ + o) * NLOC + loc] = acc[mt][nt][r] + bv;
      }
    }
  }
}

extern "C" void kernel_launch(void* const* d_in, const int* in_sizes, int n_in,
                              void* d_out, int out_size, void* d_ws, size_t ws_size,
                              hipStream_t stream) {
  const float* F = (const float*)d_in[0];
  const float* Wt = (const float*)d_in[1];
  const float* Bi = (const float*)d_in[2];
  float* Out = (float*)d_out;
  LocallyConnected2d_41102837022853_kernel<<<NLOC, 64, 0, stream>>>(F, Wt, Bi, Out);
}

// Round 2
// 797.460 us; speedup vs baseline: 1.3065x; 1.3065x over previous
//
#include <hip/hip_runtime.h>
#include <stdint.h>

// Locally connected 2d on MI355X (gfx950).
// out[b,o,h,w] = sum_{c,i,j} F[b,c,h+i,w+j] * W[h,w,o,c,i,j] + bias[h,w,o]
// B=32, Cin=Cout=64, H=W=64, K=3, Hout=Wout=62.
//
// R2 structure:
//  - prep kernel: F[b][c][h][w] fp32 -> F2[c][h][w][b] bf16 (16 MB in d_ws).
//    Makes the 32 batch values of one k-element 64 contiguous bytes.
//  - main kernel: one wave per location, GEMM M=32(b) x N=64(o) x K=576 via
//    mfma_f32_16x16x32_bf16. Weights (567 MB, read once -> the roofline)
//    feed B-frags straight from global as fp32->bf16 in registers.
//    Features: 2 coalesced dwordx4 gathers per kt from F2, b<->k transpose
//    via scalar ds_write_b16 into [b][k] LDS rows, A-frags via ds_read_b128.
//  - 256-thread blocks = 4 independent waves on 4 consecutive locations
//    (no barriers); XCD-grouped block swizzle keeps each XCD's feature
//    slice (~2.6 MB) L2-resident and merges scattered output stores.

#define B_     32
#define CIN_   64
#define H_     64
#define W_     64
#define COUT_  64
#define HOUT_  62
#define WOUT_  62
#define NLOC   (HOUT_ * WOUT_)   // 3844
#define KTOT   (CIN_ * 9)        // 576
#define NKT    (KTOT / 32)       // 18 MFMA K-steps

typedef float f32x4 __attribute__((ext_vector_type(4)));
typedef short s16x8 __attribute__((ext_vector_type(8)));
typedef uint32_t u32x4 __attribute__((ext_vector_type(4)));

// pack two fp32 -> two bf16 (RNE), lo in low half
__device__ __forceinline__ uint32_t pk_bf16(float lo, float hi) {
  uint32_t ul = __builtin_bit_cast(uint32_t, lo);
  uint32_t uh = __builtin_bit_cast(uint32_t, hi);
  ul = (ul + 0x7fffu + ((ul >> 16) & 1u)) >> 16;
  uh = (uh + 0x7fffu + ((uh >> 16) & 1u));
  return ul | (uh & 0xffff0000u);
}

// ---- prep: F[b][c][h][w] fp32 -> F2[c][h][w][b] bf16 ----
__global__ void lc2d_prep_kernel(const float* __restrict__ F,
                                 uint16_t* __restrict__ F2) {
  const int ch = blockIdx.x;      // c*64 + h, 0..4095
  const int w = threadIdx.x;      // 0..63
  const float* src = F + ch * 64 + w;   // + b*262144; lanes coalesced over w
  uint32_t pk[16];
#pragma unroll
  for (int bp = 0; bp < 16; ++bp) {
    float f0 = src[(2 * bp) * (CIN_ * H_ * W_)];
    float f1 = src[(2 * bp + 1) * (CIN_ * H_ * W_)];
    pk[bp] = pk_bf16(f0, f1);     // b even in low half -> F2[..][b] order
  }
  u32x4* dst = (u32x4*)(F2 + ((size_t)ch * 64 + w) * B_);
#pragma unroll
  for (int i = 0; i < 4; ++i) dst[i] = *(const u32x4*)&pk[4 * i];
}

// ---- main ----
__global__ __launch_bounds__(256) void LocallyConnected2d_41102837022853_kernel(
    const uint16_t* __restrict__ F2, const float* __restrict__ Wt,
    const float* __restrict__ Bi, float* __restrict__ Out) {
  // per-wave LDS: 2 ring bufs x 32 b-rows x 40 u16 (32 k + 8 pad -> 80B rows,
  // 16B-aligned b128 A-frag reads). 4 waves x 5120B = 20 KB/block.
  __shared__ __align__(16) uint16_t PL[4][2][B_][40];

  const int tid = threadIdx.x;
  const int wave = tid >> 6, lane = tid & 63;
  const int bid = blockIdx.x;

  // XCD-grouping swizzle (hw xcd ~ bid%8): each XCD gets a contiguous run of
  // 480 locations -> feature slice fits its 4MB L2, output lines merge.
  const int lb = (bid < 960) ? ((bid & 7) * 120 + (bid >> 3)) : 960;
  const int loc = lb * 4 + wave;
  const int h = loc / WOUT_, w = loc - h * WOUT_;

  const int l15 = lane & 15, l4 = lane >> 4;   // fragment coords
  const int q = lane >> 2, bo = (lane & 3) * 8;  // gather coords: 4 lanes/k

  // gather base: F2 idx = c*131072 + (h+ti)*2048 + (w+tj)*32 + b
  const uint16_t* fb = F2 + h * (W_ * B_) + w * B_ + bo;
  // B-frag lane base: o = nt*16 + l15 (row stride 576 fp32), k-slice l4*8
  const float* wlane = Wt + (size_t)loc * (COUT_ * KTOT) + (size_t)l15 * KTOT + l4 * 8;

  // per-lane gather address for k-element (16B = 8 b's of one k)
  auto gaddr = [&](int k) -> const s16x8* {
    int c = (k * 7282) >> 16;        // k/9 for k<576
    int r = k - c * 9;
    int ti = (r * 11) >> 5;          // r/3
    int tj = r - ti * 3;
    return (const s16x8*)(fb + c * (H_ * W_ * B_) + ti * (W_ * B_) + tj * B_);
  };

  // ---- prologue: gather chunk 0, weight loads kt=0 ----
  s16x8 g0 = *gaddr(q);
  s16x8 g1 = *gaddr(16 + q);
  f32x4 wv[2][4][2];
#pragma unroll
  for (int nt = 0; nt < 4; ++nt) {
    const float* p = wlane + nt * (16 * KTOT);
    wv[0][nt][0] = *(const f32x4*)p;
    wv[0][nt][1] = *(const f32x4*)(p + 4);
  }
#pragma unroll
  for (int i = 0; i < 8; ++i) {
    PL[wave][0][bo + i][q] = (uint16_t)g0[i];
    PL[wave][0][bo + i][16 + q] = (uint16_t)g1[i];
  }

  f32x4 acc[2][4] = {};

#pragma unroll
  for (int kt = 0; kt < NKT; ++kt) {
    const int cur = kt & 1, nxt = cur ^ 1;

    // 1. issue gathers for kt+1 FIRST (so weight-cvt's vmcnt wait below
    //    doesn't have to drain them), then weight prefetch kt+1.
    s16x8 h0, h1;
    if (kt + 1 < NKT) {
      h0 = *gaddr((kt + 1) * 32 + q);
      h1 = *gaddr((kt + 1) * 32 + 16 + q);
#pragma unroll
      for (int nt = 0; nt < 4; ++nt) {
        const float* p = wlane + nt * (16 * KTOT) + (kt + 1) * 32;
        wv[nxt][nt][0] = *(const f32x4*)p;
        wv[nxt][nt][1] = *(const f32x4*)(p + 4);
      }
    }

    // 2. convert current weights fp32 -> bf16 B-fragments (waits on the
    //    loads issued one full iteration ago)
    s16x8 bfrag[4];
#pragma unroll
    for (int nt = 0; nt < 4; ++nt) {
      union { uint32_t u[4]; s16x8 v; } t;
      t.u[0] = pk_bf16(wv[cur][nt][0][0], wv[cur][nt][0][1]);
      t.u[1] = pk_bf16(wv[cur][nt][0][2], wv[cur][nt][0][3]);
      t.u[2] = pk_bf16(wv[cur][nt][1][0], wv[cur][nt][1][1]);
      t.u[3] = pk_bf16(wv[cur][nt][1][2], wv[cur][nt][1][3]);
      bfrag[nt] = t.v;
    }

    // 3. A-fragments from LDS (b128, rows written one iteration ago)
    s16x8 a0 = *(const s16x8*)&PL[wave][cur][l15][l4 * 8];
    s16x8 a1 = *(const s16x8*)&PL[wave][cur][16 + l15][l4 * 8];

    // 4. 8 MFMAs: D[m=b][n=o]
#pragma unroll
    for (int nt = 0; nt < 4; ++nt) {
      acc[0][nt] = __builtin_amdgcn_mfma_f32_16x16x32_bf16(a0, bfrag[nt], acc[0][nt], 0, 0, 0);
      acc[1][nt] = __builtin_amdgcn_mfma_f32_16x16x32_bf16(a1, bfrag[nt], acc[1][nt], 0, 0, 0);
    }

    // 5. scatter kt+1 gathers into the other ring slot (b<->k transpose;
    //    scalar b16 writes, ~4-way bank aliasing, off the critical path)
    if (kt + 1 < NKT) {
#pragma unroll
      for (int i = 0; i < 8; ++i) {
        PL[wave][nxt][bo + i][q] = (uint16_t)h0[i];
        PL[wave][nxt][bo + i][16 + q] = (uint16_t)h1[i];
      }
    }
  }

  // ---- epilogue: bias + store. C/D layout: col(o)=lane&15, row(b)=l4*4+r.
#pragma unroll
  for (int nt = 0; nt < 4; ++nt) {
    const int o = nt * 16 + l15;
    const float bv = Bi[loc * COUT_ + o];
#pragma unroll
    for (int mt = 0; mt < 2; ++mt) {
#pragma unroll
      for (int r = 0; r < 4; ++r) {
        const int b = mt * 16 + l4 * 4 + r;
        Out[(size_t)(b * COUT_ + o) * NLOC + loc] = acc[mt][nt][r] + bv;
      }
    }
  }
}

extern "C" void kernel_launch(void* const* d_in, const int* in_sizes, int n_in,
                              void* d_out, int out_size, void* d_ws, size_t ws_size,
                              hipStream_t stream) {
  const float* F = (const float*)d_in[0];
  const float* Wt = (const float*)d_in[1];
  const float* Bi = (const float*)d_in[2];
  float* Out = (float*)d_out;
  uint16_t* F2 = (uint16_t*)d_ws;   // 64*64*64*32*2B = 16 MB

  lc2d_prep_kernel<<<CIN_ * H_, 64, 0, stream>>>(F, F2);
  LocallyConnected2d_41102837022853_kernel<<<NLOC / 4, 256, 0, stream>>>(F2, Wt, Bi, Out);
}